// Round 2
// baseline (2003.872 us; speedup 1.0000x reference)
//
#include <hip/hip_runtime.h>

#define B_    64
#define L1C   4093
#define L2C   4086
#define L3C   4071
#define TDEC  60

static __device__ __forceinline__ float sigf(float x){ return 1.f/(1.f + __expf(-x)); }

// ---------------- f16 pack / dot helpers ----------------
typedef _Float16 h2_t __attribute__((ext_vector_type(2)));
union U2H { unsigned u; h2_t h; };

static __device__ __forceinline__ unsigned pkh2(float a, float b){
  U2H r; r.h[0] = (_Float16)a; r.h[1] = (_Float16)b; return r.u;
}
// acc += dot(w_half2, h_half2) in fp32 — v_dot2_f32_f16 (full-rate VOP3P)
static __device__ __forceinline__ float dot2f(unsigned w, unsigned h, float acc){
  U2H a; a.u = w; U2H b; b.u = h;
#if __has_builtin(__builtin_amdgcn_fdot2)
  return __builtin_amdgcn_fdot2(a.h, b.h, acc, false);
#else
  acc = fmaf((float)a.h[0], (float)b.h[0], acc);
  acc = fmaf((float)a.h[1], (float)b.h[1], acc);
  return acc;
#endif
}

// 8 MACs from one uint4 of packed f16 weights x one uint4 of packed f16 h
#define DOT8(g, wv, hv) \
  g = dot2f(wv.x, hv.x, g); g = dot2f(wv.y, hv.y, g); \
  g = dot2f(wv.z, hv.z, g); g = dot2f(wv.w, hv.w, g);

// ---------------- conv stack (conv1, conv2: fp32 out) ----------------
template<int CIN,int COUT,int KW>
__global__ __launch_bounds__(256) void k_conv(
    const float* __restrict__ in, const float* __restrict__ w,
    const float* __restrict__ bias, float* __restrict__ outp,
    int Lin_, int Lout_)
{
  int g = blockIdx.x*256 + threadIdx.x;
  int bi = g / Lout_;
  int l  = g - bi*Lout_;
  if (bi >= B_) return;
  float acc[COUT];
#pragma unroll
  for (int o=0;o<COUT;o++) acc[o] = bias[o];
  const float* ip = in + ((size_t)bi*Lin_ + l)*CIN;
  for (int k=0;k<KW;k++){
#pragma unroll
    for (int i4=0;i4<CIN/4;i4++){
      float4 xv = *(const float4*)(ip + k*CIN + i4*4);
#pragma unroll
      for (int c=0;c<4;c++){
        float xs = (&xv.x)[c];
        int i = i4*4+c;
#pragma unroll
        for (int o=0;o<COUT;o++)
          acc[o] = fmaf(xs, w[(o*CIN + i)*KW + k], acc[o]);
      }
    }
  }
  float* op = outp + ((size_t)bi*Lout_ + l)*COUT;
#pragma unroll
  for (int o=0;o<COUT;o++) op[o] = fmaxf(acc[o],0.f);
}

// ---------------- conv3: relu + row-quantize to u8 (scale = rowmax/255) ----------------
__global__ __launch_bounds__(256) void k_conv3q(
    const float* __restrict__ in, const float* __restrict__ w,
    const float* __restrict__ bias, uint4* __restrict__ encq,
    float* __restrict__ encs, int Lin_, int Lout_)
{
  int g = blockIdx.x*256 + threadIdx.x;
  int bi = g / Lout_;
  int l  = g - bi*Lout_;
  if (bi >= B_) return;
  float acc[32];
#pragma unroll
  for (int o=0;o<32;o++) acc[o] = bias[o];
  const float* ip = in + ((size_t)bi*Lin_ + l)*16;
  for (int k=0;k<16;k++){
#pragma unroll
    for (int i4=0;i4<4;i4++){
      float4 xv = *(const float4*)(ip + k*16 + i4*4);
#pragma unroll
      for (int c=0;c<4;c++){
        float xs = (&xv.x)[c];
        int i = i4*4+c;
#pragma unroll
        for (int o=0;o<32;o++)
          acc[o] = fmaf(xs, w[(o*16 + i)*16 + k], acc[o]);
      }
    }
  }
  float mx = 0.f;
#pragma unroll
  for (int o=0;o<32;o++){ acc[o] = fmaxf(acc[o],0.f); mx = fmaxf(mx, acc[o]); }
  float scale = mx * (1.f/255.f);
  float inv = (mx > 0.f) ? (255.f/mx) : 0.f;
  unsigned qs[8];
#pragma unroll
  for (int q8=0;q8<8;q8++){
    unsigned q0 = (unsigned)(acc[q8*4+0]*inv + 0.5f);
    unsigned q1 = (unsigned)(acc[q8*4+1]*inv + 0.5f);
    unsigned q2 = (unsigned)(acc[q8*4+2]*inv + 0.5f);
    unsigned q3 = (unsigned)(acc[q8*4+3]*inv + 0.5f);
    qs[q8] = q0 | (q1<<8) | (q2<<16) | (q3<<24);
  }
  uint4* op = encq + ((size_t)bi*Lout_ + l)*2;
  op[0] = make_uint4(qs[0],qs[1],qs[2],qs[3]);
  op[1] = make_uint4(qs[4],qs[5],qs[6],qs[7]);
  encs[(size_t)bi*Lout_ + l] = scale;
}

// ---------------- pack weights: [2][1024][K] fp32 -> [2][K/8][1024] f16x8 ----------------
__global__ __launch_bounds__(256) void k_packwh(
    const float* __restrict__ w, uint4* __restrict__ wT, int K)
{
  int gid = blockIdx.x*256 + threadIdx.x;
  int per = (K/8)*1024;
  int d = gid / per, rem = gid - d*per;
  int j8 = rem >> 10, row = rem & 1023;
  const float* src = w + ((size_t)d*1024 + row)*K + j8*8;
  float4 a = *(const float4*)src;
  float4 b = *(const float4*)(src+4);
  uint4 o;
  o.x = pkh2(a.x, a.y);
  o.y = pkh2(a.z, a.w);
  o.z = pkh2(b.x, b.y);
  o.w = pkh2(b.z, b.w);
  wT[gid] = o;
}

#define CVT8(r, qv) \
  r[0]=(float)( qv.x      & 255u); r[1]=(float)((qv.x>>8 ) & 255u); \
  r[2]=(float)((qv.x>>16) & 255u); r[3]=(float)((qv.x>>24)       ); \
  r[4]=(float)( qv.y      & 255u); r[5]=(float)((qv.y>>8 ) & 255u); \
  r[6]=(float)((qv.y>>16) & 255u); r[7]=(float)((qv.y>>24)       );

// ---------------- dec1: block=(b,d); enc u8 in LDS; quad split (8ch/thread), static-bound softmax ----------------
// Gates via v_dot2_f32_f16: 4 dot instrs + 1 ds_read_b128 per 8 MACs (was 16 VALU + 2 LDS reads).
__global__ __launch_bounds__(1024) void k_dec1g(
    const uint4* __restrict__ encq,        // [B][L3C][2] uint4 (32 x u8)
    const float* __restrict__ encs,        // [B][L3C] rowscale
    const float* __restrict__ attn_w,      // [256][32]
    const uint4* __restrict__ wihT,        // [2][4][1024] f16x8 (K=32)
    const uint4* __restrict__ whhT,        // [2][32][1024] f16x8 (K=256)
    const float* __restrict__ bih, const float* __restrict__ bhh,
    float* __restrict__ d2in)              // [B][60][512]
{
  int b = blockIdx.x, d = blockIdx.y, tid = threadIdx.x;
  int c = tid & 3, rb = tid >> 2;          // quad covers rows rb+256k, k=0..15; lane owns ch c*8..c*8+7

  __shared__ __align__(16) uint2 encQ2[16384];  // 128 KB: row l = 4 uint2 (32 x u8)
  __shared__ float sls[4096];                   // 16 KB rowscales
  __shared__ __align__(16) float hls[256];      // fp32 h (attention matvec input)
  __shared__ __align__(16) unsigned h2pk[128];  // h packed f16x2 (gate dot input)
  __shared__ __align__(16) unsigned ctxh[16];   // ctx packed f16x2
  __shared__ float vl[32];
  __shared__ float maxenc[32];
  __shared__ float Msh;
  __shared__ float red[1024];
  __shared__ float scr[512];                    // [16 waves][32 ch]
  __shared__ float gls[1024];

  { // stage enc slice once (uint4-coalesced)
    const uint4* src = encq + (size_t)b*L3C*2;
    uint4* dst = (uint4*)encQ2;
    for (int i = tid; i < 8192; i += 1024)
      dst[i] = (i < L3C*2) ? src[i] : make_uint4(0,0,0,0);
    const float* ss = encs + (size_t)b*L3C;
    for (int i = tid; i < 4096; i += 1024)
      sls[i] = (i < L3C) ? ss[i] : 0.f;
  }
  if (tid < 256) hls[tid] = 0.f;
  if (tid < 128) h2pk[tid] = 0u;
  float creg = 0.f;
  float bsum = bih[(size_t)d*1024 + tid] + bhh[(size_t)d*1024 + tid];
  const uint4* whp = whhT + (size_t)d*32768;
  __syncthreads();

  { // one-time: per-channel max of real enc (>=0) -> maxenc[32]
    float mc[8];
#pragma unroll
    for (int j=0;j<8;j++) mc[j] = 0.f;
#pragma unroll
    for (int k=0;k<16;k++){
      int l = rb + 256*k;
      uint2 qv = encQ2[l*4 + c];
      float sl = sls[l];
      float r[8]; CVT8(r, qv)
#pragma unroll
      for (int j=0;j<8;j++) mc[j] = fmaxf(mc[j], r[j]*sl);
    }
#pragma unroll
    for (int off=4; off<=32; off<<=1){
#pragma unroll
      for (int j=0;j<8;j++) mc[j] = fmaxf(mc[j], __shfl_xor(mc[j], off));
    }
    int wid = tid >> 6;
    if ((tid&63) < 4){
#pragma unroll
      for (int j=0;j<8;j++) scr[wid*32 + c*8 + j] = mc[j];
    }
    __syncthreads();
    if (tid < 32){
      float mm = 0.f;
#pragma unroll
      for (int w=0;w<16;w++) mm = fmaxf(mm, scr[w*32 + tid]);
      maxenc[tid] = mm;
    }
    __syncthreads();
  }

  for (int t=0; t<TDEC; t++){
    // -- phase 1: v[c] = sum_u h[u]*attn_w[u][c]; M = sum_c maxenc[c]*max(v,0) --
    {
      int cc = tid & 31, part = tid >> 5;
      const float* wp = attn_w + (size_t)(part*8)*32 + cc;
      float s = 0.f;
#pragma unroll
      for (int k=0;k<8;k++) s = fmaf(hls[part*8+k], wp[k*32], s);
      red[tid] = s;
    }
    __syncthreads();
    if (tid < 32){
      float v = 0.f;
#pragma unroll
      for (int q=0;q<32;q++) v += red[q*32 + tid];
      vl[tid] = v;
      float mt = maxenc[tid] * fmaxf(v, 0.f);
#pragma unroll
      for (int off=1; off<32; off<<=1) mt += __shfl_xor(mt, off);
      if (tid==0) Msh = mt;
    }
    __syncthreads();

    // -- phase 2: single pass, no max tracking (M is a static bound) --
    float vreg[8];
#pragma unroll
    for (int j=0;j<8;j++) vreg[j] = vl[c*8 + j];
    float M = Msh;
    float ssum = 0.f;
    float acc[8];
#pragma unroll
    for (int j=0;j<8;j++) acc[j] = 0.f;
#pragma unroll
    for (int k=0;k<16;k++){
      int l = rb + 256*k;
      uint2 qv = encQ2[l*4 + c];
      float sl = sls[l];
      float r[8]; CVT8(r, qv)
      float s = 0.f;
#pragma unroll
      for (int j=0;j<8;j++) s = fmaf(r[j], vreg[j], s);
      s += __shfl_xor(s, 1);
      s += __shfl_xor(s, 2);
      s *= sl;
      if (k==15 && l >= L3C) s = -3.0e38f;   // only last iter can be OOB
      float e = __expf(s - M);
      ssum += e;
      float em = e * sl;
#pragma unroll
      for (int j=0;j<8;j++) acc[j] = fmaf(em, r[j], acc[j]);
    }
    // reduce: quads already share rows; butterfly across quads in wave
#pragma unroll
    for (int off=4; off<=32; off<<=1){
      ssum += __shfl_xor(ssum, off);
#pragma unroll
      for (int j=0;j<8;j++) acc[j] += __shfl_xor(acc[j], off);
    }
    int wid = tid >> 6;
    if ((tid&63) < 4){
#pragma unroll
      for (int j=0;j<8;j++) scr[wid*32 + c*8 + j] = acc[j];
    }
    if ((tid&63)==0) red[wid] = ssum;
    __syncthreads();
    if (tid < 32){
      float S = 0.f, s2 = 0.f;
#pragma unroll
      for (int w=0;w<16;w++){ S += red[w]; s2 += scr[w*32 + tid]; }
      float cv = s2 / S;
      float co = __shfl_xor(cv, 1);
      if (!(tid&1)) ctxh[tid>>1] = pkh2(cv, co);
    }
    __syncthreads();

    // -- phase 3: LSTM gates via v_dot2_f32_f16 (row = tid) --
    float g = bsum;
#pragma unroll
    for (int c8=0;c8<4;c8++){
      uint4 wv = wihT[(size_t)d*4096 + c8*1024 + tid];
      uint4 hv = *(const uint4*)&ctxh[c8*4];
      DOT8(g, wv, hv)
    }
#pragma unroll 8
    for (int j8=0;j8<32;j8++){
      uint4 wv = whp[j8*1024 + tid];
      uint4 hv = *(const uint4*)&h2pk[j8*4];
      DOT8(g, wv, hv)
    }
    gls[tid] = g;
    __syncthreads();
    if (tid < 256){
      float ii = sigf(gls[tid]);
      float ff = sigf(gls[256+tid]);
      float gg = tanhf(gls[512+tid]);
      float oo = sigf(gls[768+tid]);
      creg = fmaf(ff, creg, ii*gg);
      float hn = oo * tanhf(creg);
      hls[tid] = hn;
      float ho = __shfl_xor(hn, 1);
      if (!(tid&1)) h2pk[tid>>1] = pkh2(hn, ho);
      int tout = d ? (59 - t) : t;
      d2in[((size_t)b*60 + tout)*512 + d*256 + tid] = hn;
    }
    __syncthreads();
  }
}

// ---------------- generic fp32 GEMM ----------------
__global__ __launch_bounds__(256) void k_gemm(
    const float* __restrict__ A, const float* __restrict__ W,
    float* __restrict__ C, const float* __restrict__ b1, const float* __restrict__ b2,
    int K, int ldc, size_t sW, size_t sC, int sB)
{
  int m0 = blockIdx.x * 128, n0 = blockIdx.y * 128, z = blockIdx.z;
  const float* Wz = W + (size_t)z*sW;
  float* Cz = C + (size_t)z*sC;
  const float* b1z = b1 + (size_t)z*sB;
  const float* b2z = b2 ? (b2 + (size_t)z*sB) : nullptr;
  __shared__ __align__(16) float As[16][132];
  __shared__ __align__(16) float Bs[16][132];
  int tid = threadIdx.x;
  int tx = tid & 15, ty = tid >> 4;
  int r = tid >> 2, c4 = tid & 3;
  float acc[8][8] = {};
  for (int k0=0; k0<K; k0+=16){
#pragma unroll
    for (int h=0; h<2; h++){
      int rr = r + h*64;
      float4 av = *(const float4*)(A  + (size_t)(m0+rr)*K + k0 + c4*4);
      float4 bv = *(const float4*)(Wz + (size_t)(n0+rr)*K + k0 + c4*4);
      As[c4*4+0][rr]=av.x; As[c4*4+1][rr]=av.y; As[c4*4+2][rr]=av.z; As[c4*4+3][rr]=av.w;
      Bs[c4*4+0][rr]=bv.x; Bs[c4*4+1][rr]=bv.y; Bs[c4*4+2][rr]=bv.z; Bs[c4*4+3][rr]=bv.w;
    }
    __syncthreads();
#pragma unroll
    for (int kk=0; kk<16; kk++){
      float a[8], bb[8];
      *(float4*)&a[0]  = *(const float4*)&As[kk][ty*8];
      *(float4*)&a[4]  = *(const float4*)&As[kk][ty*8+4];
      *(float4*)&bb[0] = *(const float4*)&Bs[kk][tx*8];
      *(float4*)&bb[4] = *(const float4*)&Bs[kk][tx*8+4];
#pragma unroll
      for (int i=0;i<8;i++)
#pragma unroll
        for (int j=0;j<8;j++)
          acc[i][j] = fmaf(a[i], bb[j], acc[i][j]);
    }
    __syncthreads();
  }
  float bb1[8];
#pragma unroll
  for (int j=0;j<8;j++){
    int n = n0 + tx*8 + j;
    bb1[j] = b1z[n] + (b2z ? b2z[n] : 0.f);
  }
#pragma unroll
  for (int i=0;i<8;i++){
    int m = m0 + ty*8 + i;
    float o[8];
#pragma unroll
    for (int j=0;j<8;j++) o[j] = acc[i][j] + bb1[j];
    *(float4*)(Cz + (size_t)m*ldc + n0 + tx*8)     = *(const float4*)&o[0];
    *(float4*)(Cz + (size_t)m*ldc + n0 + tx*8 + 4) = *(const float4*)&o[4];
  }
}

// ---------------- dec2: recurrent, block = (dir, batch), 16 waves, f16 dot gates ----------------
__global__ __launch_bounds__(1024) void k_rec2(
    const float* __restrict__ xg,   // [2][64][60][1024]
    const uint4* __restrict__ wT,   // [2][32][1024] f16x8
    float* __restrict__ out)        // [64][60][512]
{
  int b = blockIdx.x, d = blockIdx.y, tid = threadIdx.x;
  __shared__ __align__(16) unsigned h2pk[128];  // h packed f16x2
  __shared__ float gls[1024];
  float c = 0.f;
  if (tid < 128) h2pk[tid] = 0u;
  __syncthreads();
  const uint4* wp = wT + (size_t)d*32*1024;
  const float* xp = xg + (((size_t)d*64 + b)*60)*1024;
  for (int step=0; step<TDEC; step++){
    int t = d ? (TDEC-1-step) : step;
    float g = xp[(size_t)t*1024 + tid];
#pragma unroll 8
    for (int j8=0;j8<32;j8++){
      uint4 wv = wp[j8*1024 + tid];
      uint4 hv = *(const uint4*)&h2pk[j8*4];
      DOT8(g, wv, hv)
    }
    gls[tid] = g;
    __syncthreads();
    if (tid < 256){
      float ii = sigf(gls[tid]);
      float ff = sigf(gls[256+tid]);
      float gg = tanhf(gls[512+tid]);
      float oo = sigf(gls[768+tid]);
      c = fmaf(ff, c, ii*gg);
      float hn = oo * tanhf(c);
      float ho = __shfl_xor(hn, 1);
      if (!(tid&1)) h2pk[tid>>1] = pkh2(hn, ho);
      out[((size_t)b*60 + t)*512 + d*256 + tid] = hn;
    }
    __syncthreads();
  }
}

extern "C" void kernel_launch(void* const* d_in, const int* in_sizes, int n_in,
                              void* d_out, int out_size, void* d_ws, size_t ws_size,
                              hipStream_t stream) {
  const float* x      = (const float*)d_in[0];
  const float* cw1    = (const float*)d_in[1];
  const float* cb1    = (const float*)d_in[2];
  const float* cw2    = (const float*)d_in[3];
  const float* cb2    = (const float*)d_in[4];
  const float* cw3    = (const float*)d_in[5];
  const float* cb3    = (const float*)d_in[6];
  const float* attn_w = (const float*)d_in[7];
  // d_in[8] attn_b: constant over softmax axis -> drops out analytically
  const float* d1_wih = (const float*)d_in[9];
  const float* d1_whh = (const float*)d_in[10];
  const float* d1_bih = (const float*)d_in[11];
  const float* d1_bhh = (const float*)d_in[12];
  const float* w2_ih0 = (const float*)d_in[13];
  const float* w2_hh0 = (const float*)d_in[14];
  const float* b2_ih0 = (const float*)d_in[15];
  const float* b2_hh0 = (const float*)d_in[16];
  const float* w2_ih1 = (const float*)d_in[17];
  const float* w2_hh1 = (const float*)d_in[18];
  const float* b2_ih1 = (const float*)d_in[19];
  const float* b2_hh1 = (const float*)d_in[20];
  const float* out_w  = (const float*)d_in[21];
  const float* out_b  = (const float*)d_in[22];

  char* ws = (char*)d_ws;
  size_t off = 0;
  // enc region: u8 enc (8.34 MB) + rowscales (1.04 MB)
  uint4* encq = (uint4*)(ws + off);                                // [B][L3C][2] uint4
  float* encs = (float*)(ws + off + 8338432);                      // [B][L3C]
  off += 16675840;
  size_t off_h1 = off;
  float* h1buf = (float*)(ws + off); off += 8382464;               // (B,4093,8)
  float* h2buf = (float*)(ws + off); off += 16736256;              // (B,4086,16)
  float* d2in  = (float*)(ws + off_h1);                            // reuse: (B,60,512)
  float* l0    = (float*)(ws + off_h1 + 7864320);
  float* l1    = (float*)(ws + off_h1 + 15728640);
  uint4* wT    = (uint4*)(ws + off_h1 + 23592960);                 // 1MB dec2 pack (dead tail)
  float* xg    = (float*)(ws + off); off += 31457280;              // [2][B][60][1024]
  // dec1 packs live INSIDE the xg region (xg written only after dec1 completes)
  uint4* d1whhT = (uint4*)xg;                                      // 1 MB
  uint4* d1wihT = (uint4*)((char*)xg + 1048576);                   // +128 KB
  (void)ws_size; (void)in_sizes; (void)n_in; (void)out_size;

  // dec1 weight packs (before dec1; clobbered later by xg — fine)
  k_packwh<<<256,256,0,stream>>>(d1_whh, d1whhT, 256);
  k_packwh<<<32, 256,0,stream>>>(d1_wih, d1wihT, 32);

  int g1 = (B_*L1C + 255)/256;
  k_conv<64,8,4><<<g1,256,0,stream>>>(x, cw1, cb1, h1buf, 4096, L1C);
  int g2 = (B_*L2C + 255)/256;
  k_conv<8,16,8><<<g2,256,0,stream>>>(h1buf, cw2, cb2, h2buf, L1C, L2C);
  int g3 = (B_*L3C + 255)/256;
  k_conv3q<<<g3,256,0,stream>>>(h2buf, cw3, cb3, encq, encs, L2C, L3C);

  // dec1: 128 independent blocks (b,d); enc u8 in LDS; quad split; static-bound softmax
  k_dec1g<<<dim3(64,2),1024,0,stream>>>(encq, encs, attn_w, d1wihT, d1whhT,
                                        d1_bih, d1_bhh, d2in);

  // dec2 layer 0
  k_packwh<<<256,256,0,stream>>>(w2_hh0, wT, 256);
  k_gemm<<<dim3(30,8,2),256,0,stream>>>(d2in, w2_ih0, xg, b2_ih0, b2_hh0,
                                        512, 1024, (size_t)1024*512, (size_t)3840*1024, 1024);
  k_rec2<<<dim3(64,2),1024,0,stream>>>(xg, wT, l0);
  // dec2 layer 1
  k_packwh<<<256,256,0,stream>>>(w2_hh1, wT, 256);
  k_gemm<<<dim3(30,8,2),256,0,stream>>>(l0, w2_ih1, xg, b2_ih1, b2_hh1,
                                        512, 1024, (size_t)1024*512, (size_t)3840*1024, 1024);
  k_rec2<<<dim3(64,2),1024,0,stream>>>(xg, wT, l1);
  // output projection
  k_gemm<<<dim3(30,1,1),256,0,stream>>>(l1, out_w, (float*)d_out, out_b, nullptr,
                                        512, 128, 0, 0, 0);
}

// Round 3
// 1606.100 us; speedup vs baseline: 1.2477x; 1.2477x over previous
//
#include <hip/hip_runtime.h>

#define B_    64
#define L1C   4093
#define L2C   4086
#define L3C   4071
#define TDEC  60

static __device__ __forceinline__ float sigf(float x){ return 1.f/(1.f + __expf(-x)); }

// ---------------- f16 pack / dot helpers ----------------
typedef _Float16 h2_t __attribute__((ext_vector_type(2)));
union U2H { unsigned u; h2_t h; };

static __device__ __forceinline__ unsigned pkh2(float a, float b){
  U2H r; r.h[0] = (_Float16)a; r.h[1] = (_Float16)b; return r.u;
}
// acc += dot(w_half2, h_half2) in fp32 — v_dot2_f32_f16 (full-rate VOP3P)
static __device__ __forceinline__ float dot2f(unsigned w, unsigned h, float acc){
  U2H a; a.u = w; U2H b; b.u = h;
#if __has_builtin(__builtin_amdgcn_fdot2)
  return __builtin_amdgcn_fdot2(a.h, b.h, acc, false);
#else
  acc = fmaf((float)a.h[0], (float)b.h[0], acc);
  acc = fmaf((float)a.h[1], (float)b.h[1], acc);
  return acc;
#endif
}

// 8 MACs from one uint4 of packed f16 weights x one uint4 of packed f16 h
#define DOT8(g, wv, hv) \
  g = dot2f(wv.x, hv.x, g); g = dot2f(wv.y, hv.y, g); \
  g = dot2f(wv.z, hv.z, g); g = dot2f(wv.w, hv.w, g);

// DPP-fused add: x + dpp_perm(x). VALU-pipe, replaces ds_swizzle shuffles.
// 0xB1 = quad_perm[1,0,3,2] (xor1), 0x4E = quad_perm[2,3,0,1] (xor2),
// 0x124 = row_ror:4, 0x128 = row_ror:8 (rotation-sum within 16-lane row,
// preserves mod-4 lane class; bitwise-identical totals for lanes 0-3).
template<int CTRL>
static __device__ __forceinline__ float dppadd(float x){
  int y = __builtin_amdgcn_update_dpp(0, __float_as_int(x), CTRL, 0xf, 0xf, true);
  return x + __int_as_float(y);
}

// ---------------- conv stack (conv1, conv2: fp32 out) ----------------
template<int CIN,int COUT,int KW>
__global__ __launch_bounds__(256) void k_conv(
    const float* __restrict__ in, const float* __restrict__ w,
    const float* __restrict__ bias, float* __restrict__ outp,
    int Lin_, int Lout_)
{
  int g = blockIdx.x*256 + threadIdx.x;
  int bi = g / Lout_;
  int l  = g - bi*Lout_;
  if (bi >= B_) return;
  float acc[COUT];
#pragma unroll
  for (int o=0;o<COUT;o++) acc[o] = bias[o];
  const float* ip = in + ((size_t)bi*Lin_ + l)*CIN;
  for (int k=0;k<KW;k++){
#pragma unroll
    for (int i4=0;i4<CIN/4;i4++){
      float4 xv = *(const float4*)(ip + k*CIN + i4*4);
#pragma unroll
      for (int c=0;c<4;c++){
        float xs = (&xv.x)[c];
        int i = i4*4+c;
#pragma unroll
        for (int o=0;o<COUT;o++)
          acc[o] = fmaf(xs, w[(o*CIN + i)*KW + k], acc[o]);
      }
    }
  }
  float* op = outp + ((size_t)bi*Lout_ + l)*COUT;
#pragma unroll
  for (int o=0;o<COUT;o++) op[o] = fmaxf(acc[o],0.f);
}

// ---------------- conv3: relu + row-quantize to u8 (scale = rowmax/255) ----------------
__global__ __launch_bounds__(256) void k_conv3q(
    const float* __restrict__ in, const float* __restrict__ w,
    const float* __restrict__ bias, uint4* __restrict__ encq,
    float* __restrict__ encs, int Lin_, int Lout_)
{
  int g = blockIdx.x*256 + threadIdx.x;
  int bi = g / Lout_;
  int l  = g - bi*Lout_;
  if (bi >= B_) return;
  float acc[32];
#pragma unroll
  for (int o=0;o<32;o++) acc[o] = bias[o];
  const float* ip = in + ((size_t)bi*Lin_ + l)*16;
  for (int k=0;k<16;k++){
#pragma unroll
    for (int i4=0;i4<4;i4++){
      float4 xv = *(const float4*)(ip + k*16 + i4*4);
#pragma unroll
      for (int c=0;c<4;c++){
        float xs = (&xv.x)[c];
        int i = i4*4+c;
#pragma unroll
        for (int o=0;o<32;o++)
          acc[o] = fmaf(xs, w[(o*16 + i)*16 + k], acc[o]);
      }
    }
  }
  float mx = 0.f;
#pragma unroll
  for (int o=0;o<32;o++){ acc[o] = fmaxf(acc[o],0.f); mx = fmaxf(mx, acc[o]); }
  float scale = mx * (1.f/255.f);
  float inv = (mx > 0.f) ? (255.f/mx) : 0.f;
  unsigned qs[8];
#pragma unroll
  for (int q8=0;q8<8;q8++){
    unsigned q0 = (unsigned)(acc[q8*4+0]*inv + 0.5f);
    unsigned q1 = (unsigned)(acc[q8*4+1]*inv + 0.5f);
    unsigned q2 = (unsigned)(acc[q8*4+2]*inv + 0.5f);
    unsigned q3 = (unsigned)(acc[q8*4+3]*inv + 0.5f);
    qs[q8] = q0 | (q1<<8) | (q2<<16) | (q3<<24);
  }
  uint4* op = encq + ((size_t)bi*Lout_ + l)*2;
  op[0] = make_uint4(qs[0],qs[1],qs[2],qs[3]);
  op[1] = make_uint4(qs[4],qs[5],qs[6],qs[7]);
  encs[(size_t)bi*Lout_ + l] = scale;
}

// ---------------- pack weights: [2][1024][K] fp32 -> [2][K/8][1024] f16x8 ----------------
__global__ __launch_bounds__(256) void k_packwh(
    const float* __restrict__ w, uint4* __restrict__ wT, int K)
{
  int gid = blockIdx.x*256 + threadIdx.x;
  int per = (K/8)*1024;
  int d = gid / per, rem = gid - d*per;
  int j8 = rem >> 10, row = rem & 1023;
  const float* src = w + ((size_t)d*1024 + row)*K + j8*8;
  float4 a = *(const float4*)src;
  float4 b = *(const float4*)(src+4);
  uint4 o;
  o.x = pkh2(a.x, a.y);
  o.y = pkh2(a.z, a.w);
  o.z = pkh2(b.x, b.y);
  o.w = pkh2(b.z, b.w);
  wT[gid] = o;
}

#define CVT8(r, qv) \
  r[0]=(float)( qv.x      & 255u); r[1]=(float)((qv.x>>8 ) & 255u); \
  r[2]=(float)((qv.x>>16) & 255u); r[3]=(float)((qv.x>>24)       ); \
  r[4]=(float)( qv.y      & 255u); r[5]=(float)((qv.y>>8 ) & 255u); \
  r[6]=(float)((qv.y>>16) & 255u); r[7]=(float)((qv.y>>24)       );

// ---------------- dec1: block=(b,d); enc u8 in LDS; quad split (8ch/thread) ----------------
// This round: (a) whh weight stream + dots fused INTO the phase-2 scoring loop
// (whh·h only needs h, which is stable since the previous step's last barrier —
// overlaps the ~3.5us/step L2 weight stream with phase-2 VALU/LDS work);
// (b) quad/butterfly reductions via DPP (VALU pipe) instead of ds_swizzle.
__global__ __launch_bounds__(1024) void k_dec1g(
    const uint4* __restrict__ encq,        // [B][L3C][2] uint4 (32 x u8)
    const float* __restrict__ encs,        // [B][L3C] rowscale
    const float* __restrict__ attn_w,      // [256][32]
    const uint4* __restrict__ wihT,        // [2][4][1024] f16x8 (K=32)
    const uint4* __restrict__ whhT,        // [2][32][1024] f16x8 (K=256)
    const float* __restrict__ bih, const float* __restrict__ bhh,
    float* __restrict__ d2in)              // [B][60][512]
{
  int b = blockIdx.x, d = blockIdx.y, tid = threadIdx.x;
  int c = tid & 3, rb = tid >> 2;          // quad covers rows rb+256k, k=0..15; lane owns ch c*8..c*8+7

  __shared__ __align__(16) uint2 encQ2[16384];  // 128 KB: row l = 4 uint2 (32 x u8)
  __shared__ float sls[4096];                   // 16 KB rowscales
  __shared__ __align__(16) float hls[256];      // fp32 h (attention matvec input)
  __shared__ __align__(16) unsigned h2pk[128];  // h packed f16x2 (gate dot input)
  __shared__ __align__(16) unsigned ctxh[16];   // ctx packed f16x2
  __shared__ float vl[32];
  __shared__ float maxenc[32];
  __shared__ float Msh;
  __shared__ float red[1024];
  __shared__ float scr[512];                    // [16 waves][32 ch]
  __shared__ float gls[1024];

  { // stage enc slice once (uint4-coalesced)
    const uint4* src = encq + (size_t)b*L3C*2;
    uint4* dst = (uint4*)encQ2;
    for (int i = tid; i < 8192; i += 1024)
      dst[i] = (i < L3C*2) ? src[i] : make_uint4(0,0,0,0);
    const float* ss = encs + (size_t)b*L3C;
    for (int i = tid; i < 4096; i += 1024)
      sls[i] = (i < L3C) ? ss[i] : 0.f;
  }
  if (tid < 256) hls[tid] = 0.f;
  if (tid < 128) h2pk[tid] = 0u;
  float creg = 0.f;
  float bsum = bih[(size_t)d*1024 + tid] + bhh[(size_t)d*1024 + tid];
  const uint4* whp = whhT + (size_t)d*32768;
  __syncthreads();

  { // one-time: per-channel max of real enc (>=0) -> maxenc[32]
    float mc[8];
#pragma unroll
    for (int j=0;j<8;j++) mc[j] = 0.f;
#pragma unroll
    for (int k=0;k<16;k++){
      int l = rb + 256*k;
      uint2 qv = encQ2[l*4 + c];
      float sl = sls[l];
      float r[8]; CVT8(r, qv)
#pragma unroll
      for (int j=0;j<8;j++) mc[j] = fmaxf(mc[j], r[j]*sl);
    }
#pragma unroll
    for (int off=4; off<=32; off<<=1){
#pragma unroll
      for (int j=0;j<8;j++) mc[j] = fmaxf(mc[j], __shfl_xor(mc[j], off));
    }
    int wid = tid >> 6;
    if ((tid&63) < 4){
#pragma unroll
      for (int j=0;j<8;j++) scr[wid*32 + c*8 + j] = mc[j];
    }
    __syncthreads();
    if (tid < 32){
      float mm = 0.f;
#pragma unroll
      for (int w=0;w<16;w++) mm = fmaxf(mm, scr[w*32 + tid]);
      maxenc[tid] = mm;
    }
    __syncthreads();
  }

  for (int t=0; t<TDEC; t++){
    // -- phase 1: v[c] = sum_u h[u]*attn_w[u][c]; M = sum_c maxenc[c]*max(v,0) --
    {
      int cc = tid & 31, part = tid >> 5;
      const float* wp = attn_w + (size_t)(part*8)*32 + cc;
      float s = 0.f;
#pragma unroll
      for (int k=0;k<8;k++) s = fmaf(hls[part*8+k], wp[k*32], s);
      red[tid] = s;
    }
    __syncthreads();
    if (tid < 32){
      float v = 0.f;
#pragma unroll
      for (int q=0;q<32;q++) v += red[q*32 + tid];
      vl[tid] = v;
      float mt = maxenc[tid] * fmaxf(v, 0.f);
#pragma unroll
      for (int off=1; off<32; off<<=1) mt += __shfl_xor(mt, off);
      if (tid==0) Msh = mt;
    }
    __syncthreads();

    // -- fused phase 2 (enc scoring, static-bound softmax) + whh·h gate stream --
    float vreg[8];
#pragma unroll
    for (int j=0;j<8;j++) vreg[j] = vl[c*8 + j];
    float M = Msh;
    float ssum = 0.f;
    float acc[8];
#pragma unroll
    for (int j=0;j<8;j++) acc[j] = 0.f;
    float g = bsum;                          // whh dots accumulate here (h stable this step)
#pragma unroll 4
    for (int k=0;k<16;k++){
      uint4 wv0 = whp[(2*k  )*1024 + tid];   // whh stream overlapped with scoring
      uint4 wv1 = whp[(2*k+1)*1024 + tid];
      int l = rb + 256*k;
      uint2 qv = encQ2[l*4 + c];
      float sl = sls[l];
      float r[8]; CVT8(r, qv)
      float s = 0.f;
#pragma unroll
      for (int j=0;j<8;j++) s = fmaf(r[j], vreg[j], s);
      s = dppadd<0xB1>(s);                   // quad xor1 (VALU)
      s = dppadd<0x4E>(s);                   // quad xor2 (VALU)
      s *= sl;
      if (l >= L3C) s = -3.0e38f;            // pad rows (only k=15 can trigger)
      float e = __expf(s - M);
      ssum += e;
      float em = e * sl;
#pragma unroll
      for (int j=0;j<8;j++) acc[j] = fmaf(em, r[j], acc[j]);
      uint4 hv0 = *(const uint4*)&h2pk[(2*k  )*4];
      uint4 hv1 = *(const uint4*)&h2pk[(2*k+1)*4];
      DOT8(g, wv0, hv0)
      DOT8(g, wv1, hv1)
    }
    // reduce across quads: row_ror4+ror8 (VALU) then xor16/xor32 (cross-row)
    ssum = dppadd<0x124>(ssum); ssum = dppadd<0x128>(ssum);
    ssum += __shfl_xor(ssum, 16); ssum += __shfl_xor(ssum, 32);
#pragma unroll
    for (int j=0;j<8;j++){
      acc[j] = dppadd<0x124>(acc[j]); acc[j] = dppadd<0x128>(acc[j]);
      acc[j] += __shfl_xor(acc[j], 16); acc[j] += __shfl_xor(acc[j], 32);
    }
    int wid = tid >> 6;
    if ((tid&63) < 4){
#pragma unroll
      for (int j=0;j<8;j++) scr[wid*32 + c*8 + j] = acc[j];
    }
    if ((tid&63)==0) red[wid] = ssum;
    __syncthreads();
    if (tid < 32){
      float S = 0.f, s2 = 0.f;
#pragma unroll
      for (int w=0;w<16;w++){ S += red[w]; s2 += scr[w*32 + tid]; }
      float cv = s2 / S;
      float co = __shfl_xor(cv, 1);
      if (!(tid&1)) ctxh[tid>>1] = pkh2(cv, co);
    }
    __syncthreads();

    // -- wih·ctx (K=32, streamed — cheap) + nonlinearity --
#pragma unroll
    for (int c8=0;c8<4;c8++){
      uint4 wv = wihT[(size_t)d*4096 + c8*1024 + tid];
      uint4 hv = *(const uint4*)&ctxh[c8*4];
      DOT8(g, wv, hv)
    }
    gls[tid] = g;
    __syncthreads();
    if (tid < 256){
      float ii = sigf(gls[tid]);
      float ff = sigf(gls[256+tid]);
      float gg = tanhf(gls[512+tid]);
      float oo = sigf(gls[768+tid]);
      creg = fmaf(ff, creg, ii*gg);
      float hn = oo * tanhf(creg);
      hls[tid] = hn;
      float ho = __shfl_xor(hn, 1);
      if (!(tid&1)) h2pk[tid>>1] = pkh2(hn, ho);
      int tout = d ? (59 - t) : t;
      d2in[((size_t)b*60 + tout)*512 + d*256 + tid] = hn;
    }
    __syncthreads();
  }
}

// ---------------- generic fp32 GEMM ----------------
__global__ __launch_bounds__(256) void k_gemm(
    const float* __restrict__ A, const float* __restrict__ W,
    float* __restrict__ C, const float* __restrict__ b1, const float* __restrict__ b2,
    int K, int ldc, size_t sW, size_t sC, int sB)
{
  int m0 = blockIdx.x * 128, n0 = blockIdx.y * 128, z = blockIdx.z;
  const float* Wz = W + (size_t)z*sW;
  float* Cz = C + (size_t)z*sC;
  const float* b1z = b1 + (size_t)z*sB;
  const float* b2z = b2 ? (b2 + (size_t)z*sB) : nullptr;
  __shared__ __align__(16) float As[16][132];
  __shared__ __align__(16) float Bs[16][132];
  int tid = threadIdx.x;
  int tx = tid & 15, ty = tid >> 4;
  int r = tid >> 2, c4 = tid & 3;
  float acc[8][8] = {};
  for (int k0=0; k0<K; k0+=16){
#pragma unroll
    for (int h=0; h<2; h++){
      int rr = r + h*64;
      float4 av = *(const float4*)(A  + (size_t)(m0+rr)*K + k0 + c4*4);
      float4 bv = *(const float4*)(Wz + (size_t)(n0+rr)*K + k0 + c4*4);
      As[c4*4+0][rr]=av.x; As[c4*4+1][rr]=av.y; As[c4*4+2][rr]=av.z; As[c4*4+3][rr]=av.w;
      Bs[c4*4+0][rr]=bv.x; Bs[c4*4+1][rr]=bv.y; Bs[c4*4+2][rr]=bv.z; Bs[c4*4+3][rr]=bv.w;
    }
    __syncthreads();
#pragma unroll
    for (int kk=0; kk<16; kk++){
      float a[8], bb[8];
      *(float4*)&a[0]  = *(const float4*)&As[kk][ty*8];
      *(float4*)&a[4]  = *(const float4*)&As[kk][ty*8+4];
      *(float4*)&bb[0] = *(const float4*)&Bs[kk][tx*8];
      *(float4*)&bb[4] = *(const float4*)&Bs[kk][tx*8+4];
#pragma unroll
      for (int i=0;i<8;i++)
#pragma unroll
        for (int j=0;j<8;j++)
          acc[i][j] = fmaf(a[i], bb[j], acc[i][j]);
    }
    __syncthreads();
  }
  float bb1[8];
#pragma unroll
  for (int j=0;j<8;j++){
    int n = n0 + tx*8 + j;
    bb1[j] = b1z[n] + (b2z ? b2z[n] : 0.f);
  }
#pragma unroll
  for (int i=0;i<8;i++){
    int m = m0 + ty*8 + i;
    float o[8];
#pragma unroll
    for (int j=0;j<8;j++) o[j] = acc[i][j] + bb1[j];
    *(float4*)(Cz + (size_t)m*ldc + n0 + tx*8)     = *(const float4*)&o[0];
    *(float4*)(Cz + (size_t)m*ldc + n0 + tx*8 + 4) = *(const float4*)&o[4];
  }
}

// ---------------- dec2: recurrent, block = (dir, batch), 16 waves ----------------
// Half the whh row (k in [0,128)) preloaded into 16 uint4 registers ONCE —
// halves the per-step L2 weight stream (the measured floor of this kernel).
// Dot accumulation order is bitwise-identical to the previous version.
__global__ __launch_bounds__(1024) void k_rec2(
    const float* __restrict__ xg,   // [2][64][60][1024]
    const uint4* __restrict__ wT,   // [2][32][1024] f16x8
    float* __restrict__ out)        // [64][60][512]
{
  int b = blockIdx.x, d = blockIdx.y, tid = threadIdx.x;
  __shared__ __align__(16) unsigned h2pk[128];  // h packed f16x2
  __shared__ float gls[1024];
  float c = 0.f;
  if (tid < 128) h2pk[tid] = 0u;
  const uint4* wp = wT + (size_t)d*32*1024;
  uint4 wpre[16];
#pragma unroll
  for (int j=0;j<16;j++) wpre[j] = wp[j*1024 + tid];   // once, not per step
  const float* xp = xg + (((size_t)d*64 + b)*60)*1024;
  __syncthreads();
  for (int step=0; step<TDEC; step++){
    int t = d ? (TDEC-1-step) : step;
    float g = xp[(size_t)t*1024 + tid];
#pragma unroll
    for (int j8=0;j8<16;j8++){                          // register-resident half
      uint4 hv = *(const uint4*)&h2pk[j8*4];
      DOT8(g, wpre[j8], hv)
    }
#pragma unroll 4
    for (int j8=16;j8<32;j8++){                         // streamed half
      uint4 wv = wp[j8*1024 + tid];
      uint4 hv = *(const uint4*)&h2pk[j8*4];
      DOT8(g, wv, hv)
    }
    gls[tid] = g;
    __syncthreads();
    if (tid < 256){
      float ii = sigf(gls[tid]);
      float ff = sigf(gls[256+tid]);
      float gg = tanhf(gls[512+tid]);
      float oo = sigf(gls[768+tid]);
      c = fmaf(ff, c, ii*gg);
      float hn = oo * tanhf(c);
      float ho = __shfl_xor(hn, 1);
      if (!(tid&1)) h2pk[tid>>1] = pkh2(hn, ho);
      out[((size_t)b*60 + t)*512 + d*256 + tid] = hn;
    }
    __syncthreads();
  }
}

extern "C" void kernel_launch(void* const* d_in, const int* in_sizes, int n_in,
                              void* d_out, int out_size, void* d_ws, size_t ws_size,
                              hipStream_t stream) {
  const float* x      = (const float*)d_in[0];
  const float* cw1    = (const float*)d_in[1];
  const float* cb1    = (const float*)d_in[2];
  const float* cw2    = (const float*)d_in[3];
  const float* cb2    = (const float*)d_in[4];
  const float* cw3    = (const float*)d_in[5];
  const float* cb3    = (const float*)d_in[6];
  const float* attn_w = (const float*)d_in[7];
  // d_in[8] attn_b: constant over softmax axis -> drops out analytically
  const float* d1_wih = (const float*)d_in[9];
  const float* d1_whh = (const float*)d_in[10];
  const float* d1_bih = (const float*)d_in[11];
  const float* d1_bhh = (const float*)d_in[12];
  const float* w2_ih0 = (const float*)d_in[13];
  const float* w2_hh0 = (const float*)d_in[14];
  const float* b2_ih0 = (const float*)d_in[15];
  const float* b2_hh0 = (const float*)d_in[16];
  const float* w2_ih1 = (const float*)d_in[17];
  const float* w2_hh1 = (const float*)d_in[18];
  const float* b2_ih1 = (const float*)d_in[19];
  const float* b2_hh1 = (const float*)d_in[20];
  const float* out_w  = (const float*)d_in[21];
  const float* out_b  = (const float*)d_in[22];

  char* ws = (char*)d_ws;
  size_t off = 0;
  // enc region: u8 enc (8.34 MB) + rowscales (1.04 MB)
  uint4* encq = (uint4*)(ws + off);                                // [B][L3C][2] uint4
  float* encs = (float*)(ws + off + 8338432);                      // [B][L3C]
  off += 16675840;
  size_t off_h1 = off;
  float* h1buf = (float*)(ws + off); off += 8382464;               // (B,4093,8)
  float* h2buf = (float*)(ws + off); off += 16736256;              // (B,4086,16)
  float* d2in  = (float*)(ws + off_h1);                            // reuse: (B,60,512)
  float* l0    = (float*)(ws + off_h1 + 7864320);
  float* l1    = (float*)(ws + off_h1 + 15728640);
  uint4* wT    = (uint4*)(ws + off_h1 + 23592960);                 // 1MB dec2 pack (dead tail)
  float* xg    = (float*)(ws + off); off += 31457280;              // [2][B][60][1024]
  // dec1 packs live INSIDE the xg region (xg written only after dec1 completes)
  uint4* d1whhT = (uint4*)xg;                                      // 1 MB
  uint4* d1wihT = (uint4*)((char*)xg + 1048576);                   // +128 KB
  (void)ws_size; (void)in_sizes; (void)n_in; (void)out_size;

  // dec1 weight packs (before dec1; clobbered later by xg — fine)
  k_packwh<<<256,256,0,stream>>>(d1_whh, d1whhT, 256);
  k_packwh<<<32, 256,0,stream>>>(d1_wih, d1wihT, 32);

  int g1 = (B_*L1C + 255)/256;
  k_conv<64,8,4><<<g1,256,0,stream>>>(x, cw1, cb1, h1buf, 4096, L1C);
  int g2 = (B_*L2C + 255)/256;
  k_conv<8,16,8><<<g2,256,0,stream>>>(h1buf, cw2, cb2, h2buf, L1C, L2C);
  int g3 = (B_*L3C + 255)/256;
  k_conv3q<<<g3,256,0,stream>>>(h2buf, cw3, cb3, encq, encs, L2C, L3C);

  // dec1: 128 independent blocks (b,d); enc u8 in LDS; fused score+gate stream
  k_dec1g<<<dim3(64,2),1024,0,stream>>>(encq, encs, attn_w, d1wihT, d1whhT,
                                        d1_bih, d1_bhh, d2in);

  // dec2 layer 0
  k_packwh<<<256,256,0,stream>>>(w2_hh0, wT, 256);
  k_gemm<<<dim3(30,8,2),256,0,stream>>>(d2in, w2_ih0, xg, b2_ih0, b2_hh0,
                                        512, 1024, (size_t)1024*512, (size_t)3840*1024, 1024);
  k_rec2<<<dim3(64,2),1024,0,stream>>>(xg, wT, l0);
  // dec2 layer 1
  k_packwh<<<256,256,0,stream>>>(w2_hh1, wT, 256);
  k_gemm<<<dim3(30,8,2),256,0,stream>>>(l0, w2_ih1, xg, b2_ih1, b2_hh1,
                                        512, 1024, (size_t)1024*512, (size_t)3840*1024, 1024);
  k_rec2<<<dim3(64,2),1024,0,stream>>>(xg, wT, l1);
  // output projection
  k_gemm<<<dim3(30,1,1),256,0,stream>>>(l1, out_w, (float*)d_out, out_b, nullptr,
                                        512, 128, 0, 0, 0);
}